// Round 6
// baseline (125.225 us; speedup 1.0000x reference)
//
#include <hip/hip_runtime.h>

#define B_  8
#define S_  1024
#define E_  512
#define TI  64
#define TJ  64
#define LOG2E 1.44269504088896340736f

typedef _Float16 half_t;
typedef _Float16 half2_t __attribute__((ext_vector_type(2)));
typedef _Float16 half8_t __attribute__((ext_vector_type(8)));
typedef float    floatx16 __attribute__((ext_vector_type(16)));
typedef unsigned int uint2v __attribute__((ext_vector_type(2)));
typedef unsigned int uint4v __attribute__((ext_vector_type(4)));

#define PHI_BYTES ((size_t)64 * S_ * 32 * 2)       // 4 MB per phi table
#define VT_BYTES  ((size_t)64 * 16 * 4096 * 2)     // 8 MB (tiled)

#define GLOAD_LDS16(g, l)                                                        \
    __builtin_amdgcn_global_load_lds((const __attribute__((address_space(1))) void*)(g), \
                                     (__attribute__((address_space(3))) void*)(l), 16, 0, 0)

// ---------------------------------------------------------------------------
// Precompute (unchanged from passing r5): Phi tables (B = exact f16 features;
// A = H-block pre-scaled by log2e in f32 before the single f16 rounding) and
// V^T tiled as the exact per-chunk LDS image [bh][chunk][slot][d][e] f16.
// 1D grid 1024 with XCD bh-affinity swizzle matching attn.
// ---------------------------------------------------------------------------
__global__ __launch_bounds__(256, 4) void precompute_kernel(const float* __restrict__ x,
                                                            half_t* __restrict__ phiA,
                                                            half_t* __restrict__ phiB,
                                                            half_t* __restrict__ vt) {
    const int orig = blockIdx.x;
    const int xcd  = orig & 7, slot = orig >> 3;
    const int bh   = xcd * 8 + (slot & 7);      // 8 bh per XCD (matches attn)
    const int chunk = slot >> 3;                 // 16 j-chunks
    const int b  = bh >> 3, h = bh & 7;
    const int j0 = chunk * 64;
    const int t  = threadIdx.x;
    __shared__ __align__(16) float vf[64][76];   // stride 304 B (16B-aligned)

    const float* xb = x + (size_t)b * S_ * E_ + h * 64;

    // Phase A: 64 j x 64 d floats, float4 loads
    {
        const int j = t >> 2, dq = (t & 3) * 4;
        const float* row = xb + (size_t)(j0 + j) * E_;
        #pragma unroll
        for (int q = 0; q < 4; ++q)
            *(float4*)&vf[j][dq + q * 16] = *(const float4*)(row + dq + q * 16);
    }
    __syncthreads();

    // Phase B1 (threads 0..127): Phi features (math identical to verified r1)
    if (t < 128) {
        const int jj = t >> 1, sel = t & 1;      // sel=1 -> wires 4..7 (H block)
        float4 xw = *(const float4*)&vf[jj][sel * 4];
        float xi[4] = {xw.x, xw.y, xw.z, xw.w};
        float c[4], s[4];
        #pragma unroll
        for (int q = 0; q < 4; ++q) {
            float v = xi[q] * 0.5f;
            c[q] = __cosf(v); s[q] = __sinf(v);
        }
        float pa[4] = {c[0]*c[1], s[0]*c[1], c[0]*s[1], s[0]*s[1]};
        float pb[4] = {c[2]*c[3], s[2]*c[3], c[2]*s[3], s[2]*s[3]};
        const float scale = sel ? LOG2E : 1.0f;   // scale H features in A table only
        half_t hB[16], hA[16];
        #pragma unroll
        for (int f = 0; f < 16; ++f) {
            float v = pa[f & 3] * pb[f >> 2];
            hB[f] = (half_t)v;
            hA[f] = (half_t)(v * scale);
        }
        size_t off = ((size_t)bh * S_ + j0 + jj) * 32 + (sel ? 0 : 16);
        *(half8_t*)(phiB + off)     = *(half8_t*)&hB[0];
        *(half8_t*)(phiB + off + 8) = *(half8_t*)&hB[8];
        *(half8_t*)(phiA + off)     = *(half8_t*)&hA[0];
        *(half8_t*)(phiA + off + 8) = *(half8_t*)&hA[8];
    }

    // Phase B2: V^T tiled — thread owns (d, 16 consecutive j = 2 slots)
    {
        const int d = t >> 2, jg = (t & 3) * 16;
        half_t hv[16];
        #pragma unroll
        for (int k = 0; k < 16; ++k) hv[k] = (half_t)vf[jg + k][d];
        const int slot0 = (t & 3) * 2;
        half_t* base = vt + ((size_t)bh * 16 + chunk) * 4096;
        *(half8_t*)(base + (slot0 + 0) * 512 + d * 8) = *(half8_t*)&hv[0];
        *(half8_t*)(base + (slot0 + 1) * 512 + d * 8) = *(half8_t*)&hv[8];
    }
}

// ---------------------------------------------------------------------------
// Main kernel. 1D grid 1024, XCD bh-affinity swizzle. 4 waves = 2 i-bands x
// 2 j-bands. PREFETCH DISTANCE 2: V quad-buffered (sh_v[4], 32 KB, unioned
// with epilogue sh_red), aj Phi-frags in a 2-deep register pipeline. Steady
// waitcnt = vmcnt(4) (two chunk-groups in flight), drain-to-0 only at tt=14.
// Loop unrolled x4 so buffer indices/reg shifts are compile-time. Output
// stores nontemporal (keep phi/vt resident in L2).
// ---------------------------------------------------------------------------
__global__ __launch_bounds__(256, 4) void attn_kernel(const half_t* __restrict__ phiA,
                                                      const half_t* __restrict__ phiB,
                                                      const half_t* __restrict__ vt,
                                                      float* __restrict__ out) {
    const int orig = blockIdx.x;
    const int xcd  = orig & 7, slot = orig >> 3;
    const int bh   = xcd * 8 + (slot & 7);      // 8 bh per XCD
    const int iblk = slot >> 3;                  // 16 i-blocks
    const int b    = bh >> 3, h = bh & 7;
    const int i0   = iblk * TI;
    const int t    = threadIdx.x;
    const int wv   = t >> 6, ln = t & 63;
    const int m    = ln & 31, hf = ln >> 5;
    const int ib   = wv >> 1, jb = wv & 1;

    // sh_v (main loop, 32 KB) and sh_red (epilogue only, 16 KB) share storage;
    // lifetimes disjoint, separated by a full __syncthreads() drain.
    __shared__ __align__(16) unsigned char smem_u[32768];
    half_t (&sh_v)[4][4096]     = *reinterpret_cast<half_t(*)[4][4096]>(smem_u);
    float  (&sh_red)[2][32][64] = *reinterpret_cast<float(*)[2][32][64]>(smem_u);
    __shared__ float sh_den[2][64];

    const half_t* phbA = phiA + (size_t)bh * S_ * 32;
    const half_t* phbB = phiB + (size_t)bh * S_ * 32;
    const half_t* vtb  = vt + (size_t)bh * 16 * 4096;

    half8_t biH, biL;
    {
        const half_t* pr = phbB + (size_t)(i0 + ib * 32 + m) * 32 + hf * 8;
        biH = *(const half8_t*)pr;
        biL = *(const half8_t*)(pr + 16);
    }

    floatx16 acc0, acc1, z;
    #pragma unroll
    for (int k = 0; k < 16; ++k) { acc0[k] = 0.f; acc1[k] = 0.f; z[k] = 0.f; }
    float d0 = 0.f, d1 = 0.f;

    const half_t* asrc = phbA + (size_t)(jb * 32 + m) * 32 + hf * 8;
    const int s0 = 2 * wv, s1 = 2 * wv + 1;

    // prologue: stage chunks 0,1 and load aj(0),aj(1) — two groups in flight
    GLOAD_LDS16(vtb + 0 * 4096 + s0 * 512 + ln * 8, &sh_v[0][s0 * 512]);
    GLOAD_LDS16(vtb + 0 * 4096 + s1 * 512 + ln * 8, &sh_v[0][s1 * 512]);
    half8_t a0H = *(const half8_t*)(asrc);
    half8_t a0L = *(const half8_t*)(asrc + 16);
    GLOAD_LDS16(vtb + 1 * 4096 + s0 * 512 + ln * 8, &sh_v[1][s0 * 512]);
    GLOAD_LDS16(vtb + 1 * 4096 + s1 * 512 + ln * 8, &sh_v[1][s1 * 512]);
    half8_t a1H = *(const half8_t*)(asrc + 2048);
    half8_t a1L = *(const half8_t*)(asrc + 2048 + 16);
    __builtin_amdgcn_sched_barrier(0);
    asm volatile("s_waitcnt vmcnt(4)" ::: "memory");   // group(0) landed
    __builtin_amdgcn_s_barrier();

    #pragma unroll 4
    for (int tt = 0; tt < 16; ++tt) {
        const int cur = tt & 3;
        const int far = (tt + 2) & 3;   // compile-time within unrolled bodies

        // issue group(tt+2): V stage + aj load, distance-2 ahead.
        // WAR-safe: buf[far] was last read at chunk tt-2; its readers completed
        // before the end-of-(tt-2) barrier.
        half8_t a2H, a2L;
        if (tt < 14) {
            const half_t* vs = vtb + (size_t)(tt + 2) * 4096;
            GLOAD_LDS16(vs + s0 * 512 + ln * 8, &sh_v[far][s0 * 512]);
            GLOAD_LDS16(vs + s1 * 512 + ln * 8, &sh_v[far][s1 * 512]);
            const half_t* ar = asrc + (size_t)(tt + 2) * 2048;
            a2H = *(const half8_t*)ar;
            a2L = *(const half8_t*)(ar + 16);
        } else { a2H = a0H; a2L = a0L; }
        __builtin_amdgcn_sched_barrier(0);   // pin issue order: group boundary

        // B-frags for current chunk (lane-linear ds_read_b128, conflict-free)
        const half_t* vb = sh_v[cur];
        const int q0 = jb * 4;
        half8_t b00 = *(const half8_t*)&vb[(q0 + 0 + hf) * 512 + m * 8];
        half8_t b01 = *(const half8_t*)&vb[(q0 + 2 + hf) * 512 + m * 8];
        half8_t b10 = *(const half8_t*)&vb[(q0 + 0 + hf) * 512 + (32 + m) * 8];
        half8_t b11 = *(const half8_t*)&vb[(q0 + 2 + hf) * 512 + (32 + m) * 8];

        // S^T: lane holds j=(r&3)+8*(r>>2)+4*hf (own band), i=m
        floatx16 sH = __builtin_amdgcn_mfma_f32_32x32x16_f16(a0H, biH, z, 0, 0, 0);
        floatx16 sL = __builtin_amdgcn_mfma_f32_32x32x16_f16(a0L, biL, z, 0, 0, 0);

        // P = 2^|sH'*sL| = e^|s| (H pre-scaled by log2e) — packed in registers
        unsigned int dwa[4], dwb[4];
        #pragma unroll
        for (int g = 0; g < 4; ++g) {
            float p[4];
            #pragma unroll
            for (int r = 0; r < 4; ++r) {
                float sc = sH[4 * g + r] * sL[4 * g + r];
                p[r] = __builtin_amdgcn_exp2f(__builtin_fabsf(sc));
            }
            d0 += p[0] + p[2];
            d1 += p[1] + p[3];
            half2_t ha = {(half_t)p[0], (half_t)p[1]};
            half2_t hb = {(half_t)p[2], (half_t)p[3]};
            dwa[g] = __builtin_bit_cast(unsigned int, ha);
            dwb[g] = __builtin_bit_cast(unsigned int, hb);
        }
        uint2v swA0 = __builtin_amdgcn_permlane32_swap(dwa[0], dwa[1], false, false);
        uint2v swB0 = __builtin_amdgcn_permlane32_swap(dwb[0], dwb[1], false, false);
        uint2v swA1 = __builtin_amdgcn_permlane32_swap(dwa[2], dwa[3], false, false);
        uint2v swB1 = __builtin_amdgcn_permlane32_swap(dwb[2], dwb[3], false, false);
        half8_t ap0 = __builtin_bit_cast(half8_t, (uint4v){swA0.x, swB0.x, swA0.y, swB0.y});
        half8_t ap1 = __builtin_bit_cast(half8_t, (uint4v){swA1.x, swB1.x, swA1.y, swB1.y});

        acc0 = __builtin_amdgcn_mfma_f32_32x32x16_f16(ap0, b00, acc0, 0, 0, 0);
        acc0 = __builtin_amdgcn_mfma_f32_32x32x16_f16(ap1, b01, acc0, 0, 0, 0);
        acc1 = __builtin_amdgcn_mfma_f32_32x32x16_f16(ap0, b10, acc1, 0, 0, 0);
        acc1 = __builtin_amdgcn_mfma_f32_32x32x16_f16(ap1, b11, acc1, 0, 0, 0);

        // counted handoff: drain group(tt+1) only; group(tt+2) stays in flight
        if (tt < 14)       { asm volatile("s_waitcnt vmcnt(4)" ::: "memory"); }
        else if (tt == 14) { asm volatile("s_waitcnt vmcnt(0)" ::: "memory"); }
        __builtin_amdgcn_s_barrier();

        // shift the aj register pipeline (renamed away by the x4 unroll)
        a0H = a1H; a0L = a1L; a1H = a2H; a1L = a2L;
    }

    // full drain before reusing sh_v's storage as sh_red
    __syncthreads();

    // ---- epilogue: combine hf halves of denominator, then jb partials of O
    float dtot = d0 + d1;
    dtot += __shfl_xor(dtot, 32, 64);
    sh_den[jb][ib * 32 + m] = dtot;
    if (jb == 1) {
        #pragma unroll
        for (int reg = 0; reg < 16; ++reg) {
            int il = (reg & 3) + 8 * (reg >> 2) + 4 * hf;
            sh_red[ib][il][m]      = acc0[reg];
            sh_red[ib][il][32 + m] = acc1[reg];
        }
    }
    __syncthreads();
    if (jb == 0) {
        #pragma unroll
        for (int reg = 0; reg < 16; ++reg) {
            int il = (reg & 3) + 8 * (reg >> 2) + 4 * hf;
            float inv = 1.f / (sh_den[0][ib * 32 + il] + sh_den[1][ib * 32 + il]);
            size_t base = ((size_t)(b * S_ + i0 + ib * 32 + il)) * E_ + h * 64 + m;
            __builtin_nontemporal_store((acc0[reg] + sh_red[ib][il][m])      * inv, &out[base]);
            __builtin_nontemporal_store((acc1[reg] + sh_red[ib][il][32 + m]) * inv, &out[base + 32]);
        }
    }
}

extern "C" void kernel_launch(void* const* d_in, const int* in_sizes, int n_in,
                              void* d_out, int out_size, void* d_ws, size_t ws_size,
                              hipStream_t stream) {
    const float* x = (const float*)d_in[0];
    float* out = (float*)d_out;
    half_t* phiA = (half_t*)d_ws;
    half_t* phiB = (half_t*)((char*)d_ws + PHI_BYTES);
    half_t* vt   = (half_t*)((char*)d_ws + 2 * PHI_BYTES);
    precompute_kernel<<<dim3(1024), 256, 0, stream>>>(x, phiA, phiB, vt);
    attn_kernel<<<dim3(1024), 256, 0, stream>>>(phiA, phiB, vt, out);
}

// Round 7
// 93.666 us; speedup vs baseline: 1.3369x; 1.3369x over previous
//
#include <hip/hip_runtime.h>

#define B_  8
#define S_  1024
#define E_  512
#define TI  64
#define TJ  64
#define LOG2E 1.44269504088896340736f

typedef _Float16 half_t;
typedef _Float16 half2_t __attribute__((ext_vector_type(2)));
typedef _Float16 half8_t __attribute__((ext_vector_type(8)));
typedef float    floatx16 __attribute__((ext_vector_type(16)));
typedef unsigned int uint2v __attribute__((ext_vector_type(2)));
typedef unsigned int uint4v __attribute__((ext_vector_type(4)));

#define PHI_BYTES ((size_t)64 * S_ * 32 * 2)       // 4 MB per phi table
#define VT_BYTES  ((size_t)64 * 16 * 4096 * 2)     // 8 MB (tiled)

#define GLOAD_LDS16(g, l)                                                        \
    __builtin_amdgcn_global_load_lds((const __attribute__((address_space(1))) void*)(g), \
                                     (__attribute__((address_space(3))) void*)(l), 16, 0, 0)

// ---------------------------------------------------------------------------
// Precompute (byte-identical to the r5 passing version): Phi tables (B = exact
// f16 features; A = H-block pre-scaled by log2e in f32 before the single f16
// rounding) and V^T tiled as the exact per-chunk LDS image
// [bh][chunk][slot][d][e] f16. 1D grid 1024 with XCD bh-affinity swizzle.
// ---------------------------------------------------------------------------
__global__ __launch_bounds__(256, 4) void precompute_kernel(const float* __restrict__ x,
                                                            half_t* __restrict__ phiA,
                                                            half_t* __restrict__ phiB,
                                                            half_t* __restrict__ vt) {
    const int orig = blockIdx.x;
    const int xcd  = orig & 7, slot = orig >> 3;
    const int bh   = xcd * 8 + (slot & 7);      // 8 bh per XCD (matches attn)
    const int chunk = slot >> 3;                 // 16 j-chunks
    const int b  = bh >> 3, h = bh & 7;
    const int j0 = chunk * 64;
    const int t  = threadIdx.x;
    __shared__ __align__(16) float vf[64][76];   // stride 304 B (16B-aligned)

    const float* xb = x + (size_t)b * S_ * E_ + h * 64;

    // Phase A: 64 j x 64 d floats, float4 loads
    {
        const int j = t >> 2, dq = (t & 3) * 4;
        const float* row = xb + (size_t)(j0 + j) * E_;
        #pragma unroll
        for (int q = 0; q < 4; ++q)
            *(float4*)&vf[j][dq + q * 16] = *(const float4*)(row + dq + q * 16);
    }
    __syncthreads();

    // Phase B1 (threads 0..127): Phi features (math identical to verified r1)
    if (t < 128) {
        const int jj = t >> 1, sel = t & 1;      // sel=1 -> wires 4..7 (H block)
        float4 xw = *(const float4*)&vf[jj][sel * 4];
        float xi[4] = {xw.x, xw.y, xw.z, xw.w};
        float c[4], s[4];
        #pragma unroll
        for (int q = 0; q < 4; ++q) {
            float v = xi[q] * 0.5f;
            c[q] = __cosf(v); s[q] = __sinf(v);
        }
        float pa[4] = {c[0]*c[1], s[0]*c[1], c[0]*s[1], s[0]*s[1]};
        float pb[4] = {c[2]*c[3], s[2]*c[3], c[2]*s[3], s[2]*s[3]};
        const float scale = sel ? LOG2E : 1.0f;   // scale H features in A table only
        half_t hB[16], hA[16];
        #pragma unroll
        for (int f = 0; f < 16; ++f) {
            float v = pa[f & 3] * pb[f >> 2];
            hB[f] = (half_t)v;
            hA[f] = (half_t)(v * scale);
        }
        size_t off = ((size_t)bh * S_ + j0 + jj) * 32 + (sel ? 0 : 16);
        *(half8_t*)(phiB + off)     = *(half8_t*)&hB[0];
        *(half8_t*)(phiB + off + 8) = *(half8_t*)&hB[8];
        *(half8_t*)(phiA + off)     = *(half8_t*)&hA[0];
        *(half8_t*)(phiA + off + 8) = *(half8_t*)&hA[8];
    }

    // Phase B2: V^T tiled — thread owns (d, 16 consecutive j = 2 slots)
    {
        const int d = t >> 2, jg = (t & 3) * 16;
        half_t hv[16];
        #pragma unroll
        for (int k = 0; k < 16; ++k) hv[k] = (half_t)vf[jg + k][d];
        const int slot0 = (t & 3) * 2;
        half_t* base = vt + ((size_t)bh * 16 + chunk) * 4096;
        *(half8_t*)(base + (slot0 + 0) * 512 + d * 8) = *(half8_t*)&hv[0];
        *(half8_t*)(base + (slot0 + 1) * 512 + d * 8) = *(half8_t*)&hv[8];
    }
}

// ---------------------------------------------------------------------------
// Main kernel. 1D grid 1024, XCD bh-affinity swizzle. 4 waves = 2 i-bands x
// 2 j-bands. Structure = the best-measured r5 pipeline: distance-1 V double
// buffer via lane-linear global_load_lds, wrapped Phi_j register prefetch,
// counted s_waitcnt vmcnt(2), one barrier per chunk, unroll 2.
// KEY CHANGE: __launch_bounds__(256, 2) -> 256 unified VGPRs/wave. The
// (256,3)/(256,4) variants capped arch VGPRs at 64 and spilled ~100 MB to
// scratch (r3: WRITE 280 MB, r6: 112 MB vs 16 MB output). 2 blocks/CU costs
// nothing (r5 measured occupancy 3->4 = zero delta); unspilling is pure win.
// ---------------------------------------------------------------------------
__global__ __launch_bounds__(256, 2) void attn_kernel(const half_t* __restrict__ phiA,
                                                      const half_t* __restrict__ phiB,
                                                      const half_t* __restrict__ vt,
                                                      float* __restrict__ out) {
    const int orig = blockIdx.x;
    const int xcd  = orig & 7, slot = orig >> 3;
    const int bh   = xcd * 8 + (slot & 7);      // 8 bh per XCD
    const int iblk = slot >> 3;                  // 16 i-blocks
    const int b    = bh >> 3, h = bh & 7;
    const int i0   = iblk * TI;
    const int t    = threadIdx.x;
    const int wv   = t >> 6, ln = t & 63;
    const int m    = ln & 31, hf = ln >> 5;
    const int ib   = wv >> 1, jb = wv & 1;

    // sh_v (main loop) and sh_red (epilogue only) share storage: lifetimes are
    // disjoint, separated by a full __syncthreads() drain after the loop.
    __shared__ __align__(16) unsigned char smem_u[16384];
    half_t (&sh_v)[2][4096]     = *reinterpret_cast<half_t(*)[2][4096]>(smem_u);
    float  (&sh_red)[2][32][64] = *reinterpret_cast<float(*)[2][32][64]>(smem_u);
    __shared__ float sh_den[2][64];

    const half_t* phbA = phiA + (size_t)bh * S_ * 32;
    const half_t* phbB = phiB + (size_t)bh * S_ * 32;
    const half_t* vtb  = vt + (size_t)bh * 16 * 4096;

    half8_t biH, biL;
    {
        const half_t* pr = phbB + (size_t)(i0 + ib * 32 + m) * 32 + hf * 8;
        biH = *(const half8_t*)pr;
        biL = *(const half8_t*)(pr + 16);
    }

    floatx16 acc0, acc1, z;
    #pragma unroll
    for (int k = 0; k < 16; ++k) { acc0[k] = 0.f; acc1[k] = 0.f; z[k] = 0.f; }
    float d0 = 0.f, d1 = 0.f;

    const half_t* asrc = phbA + (size_t)(jb * 32 + m) * 32 + hf * 8;
    const int s0 = 2 * wv, s1 = 2 * wv + 1;

    // prologue: stage chunk 0 into buf0 (lane-linear, coalesced), prefetch aj(0)
    GLOAD_LDS16(vtb + s0 * 512 + ln * 8, &sh_v[0][s0 * 512]);
    GLOAD_LDS16(vtb + s1 * 512 + ln * 8, &sh_v[0][s1 * 512]);
    __builtin_amdgcn_sched_barrier(0);
    half8_t ajH = *(const half8_t*)(asrc);
    half8_t ajL = *(const half8_t*)(asrc + 16);
    asm volatile("s_waitcnt vmcnt(2)" ::: "memory");   // stages landed (aj in flight)
    __builtin_amdgcn_s_barrier();

    #pragma unroll 2
    for (int tt = 0; tt < 16; ++tt) {
        const int cur = tt & 1;
        const int ntt = (tt + 1) & 15;   // wrapped: always-valid prefetch address

        // stage next chunk into the other buffer (WAR-safe: its readers all
        // passed the previous end-of-chunk barrier)
        if (tt < 15) {
            const half_t* vs = vtb + (size_t)ntt * 4096;
            GLOAD_LDS16(vs + s0 * 512 + ln * 8, &sh_v[cur ^ 1][s0 * 512]);
            GLOAD_LDS16(vs + s1 * 512 + ln * 8, &sh_v[cur ^ 1][s1 * 512]);
        }
        __builtin_amdgcn_sched_barrier(0);   // pin: stages before aj loads

        // B-frags for current chunk (lane-linear ds_read_b128, conflict-free)
        const half_t* vb = sh_v[cur];
        const int q0 = jb * 4;
        half8_t b00 = *(const half8_t*)&vb[(q0 + 0 + hf) * 512 + m * 8];
        half8_t b01 = *(const half8_t*)&vb[(q0 + 2 + hf) * 512 + m * 8];
        half8_t b10 = *(const half8_t*)&vb[(q0 + 0 + hf) * 512 + (32 + m) * 8];
        half8_t b11 = *(const half8_t*)&vb[(q0 + 2 + hf) * 512 + (32 + m) * 8];

        // register-prefetch next chunk's Phi_j (branch-free, wrapped)
        const half_t* ar = asrc + (size_t)(ntt * TJ) * 32;
        half8_t ajHn = *(const half8_t*)ar;
        half8_t ajLn = *(const half8_t*)(ar + 16);

        // S^T: lane holds j=(r&3)+8*(r>>2)+4*hf (own band), i=m
        floatx16 sH = __builtin_amdgcn_mfma_f32_32x32x16_f16(ajH, biH, z, 0, 0, 0);
        floatx16 sL = __builtin_amdgcn_mfma_f32_32x32x16_f16(ajL, biL, z, 0, 0, 0);

        // P = 2^|sH'*sL| = e^|s| (H pre-scaled by log2e) — packed in registers
        unsigned int dwa[4], dwb[4];
        #pragma unroll
        for (int g = 0; g < 4; ++g) {
            float p[4];
            #pragma unroll
            for (int r = 0; r < 4; ++r) {
                float sc = sH[4 * g + r] * sL[4 * g + r];
                p[r] = __builtin_amdgcn_exp2f(__builtin_fabsf(sc));
            }
            d0 += p[0] + p[2];
            d1 += p[1] + p[3];
            half2_t ha = {(half_t)p[0], (half_t)p[1]};
            half2_t hb = {(half_t)p[2], (half_t)p[3]};
            dwa[g] = __builtin_bit_cast(unsigned int, ha);
            dwb[g] = __builtin_bit_cast(unsigned int, hb);
        }
        uint2v swA0 = __builtin_amdgcn_permlane32_swap(dwa[0], dwa[1], false, false);
        uint2v swB0 = __builtin_amdgcn_permlane32_swap(dwb[0], dwb[1], false, false);
        uint2v swA1 = __builtin_amdgcn_permlane32_swap(dwa[2], dwa[3], false, false);
        uint2v swB1 = __builtin_amdgcn_permlane32_swap(dwb[2], dwb[3], false, false);
        half8_t ap0 = __builtin_bit_cast(half8_t, (uint4v){swA0.x, swB0.x, swA0.y, swB0.y});
        half8_t ap1 = __builtin_bit_cast(half8_t, (uint4v){swA1.x, swB1.x, swA1.y, swB1.y});

        acc0 = __builtin_amdgcn_mfma_f32_32x32x16_f16(ap0, b00, acc0, 0, 0, 0);
        acc0 = __builtin_amdgcn_mfma_f32_32x32x16_f16(ap1, b01, acc0, 0, 0, 0);
        acc1 = __builtin_amdgcn_mfma_f32_32x32x16_f16(ap0, b10, acc1, 0, 0, 0);
        acc1 = __builtin_amdgcn_mfma_f32_32x32x16_f16(ap1, b11, acc1, 0, 0, 0);

        // counted handoff: own stages retired (aj prefetch stays in flight)
        if (tt < 15) { asm volatile("s_waitcnt vmcnt(2)" ::: "memory"); }
        __builtin_amdgcn_s_barrier();
        ajH = ajHn; ajL = ajLn;
    }

    // full drain before reusing sh_v's storage as sh_red
    __syncthreads();

    // ---- epilogue: combine hf halves of denominator, then jb partials of O
    float dtot = d0 + d1;
    dtot += __shfl_xor(dtot, 32, 64);
    sh_den[jb][ib * 32 + m] = dtot;
    if (jb == 1) {
        #pragma unroll
        for (int reg = 0; reg < 16; ++reg) {
            int il = (reg & 3) + 8 * (reg >> 2) + 4 * hf;
            sh_red[ib][il][m]      = acc0[reg];
            sh_red[ib][il][32 + m] = acc1[reg];
        }
    }
    __syncthreads();
    if (jb == 0) {
        #pragma unroll
        for (int reg = 0; reg < 16; ++reg) {
            int il = (reg & 3) + 8 * (reg >> 2) + 4 * hf;
            float inv = 1.f / (sh_den[0][ib * 32 + il] + sh_den[1][ib * 32 + il]);
            size_t base = ((size_t)(b * S_ + i0 + ib * 32 + il)) * E_ + h * 64 + m;
            __builtin_nontemporal_store((acc0[reg] + sh_red[ib][il][m])      * inv, &out[base]);
            __builtin_nontemporal_store((acc1[reg] + sh_red[ib][il][32 + m]) * inv, &out[base + 32]);
        }
    }
}

extern "C" void kernel_launch(void* const* d_in, const int* in_sizes, int n_in,
                              void* d_out, int out_size, void* d_ws, size_t ws_size,
                              hipStream_t stream) {
    const float* x = (const float*)d_in[0];
    float* out = (float*)d_out;
    half_t* phiA = (half_t*)d_ws;
    half_t* phiB = (half_t*)((char*)d_ws + PHI_BYTES);
    half_t* vt   = (half_t*)((char*)d_ws + 2 * PHI_BYTES);
    precompute_kernel<<<dim3(1024), 256, 0, stream>>>(x, phiA, phiB, vt);
    attn_kernel<<<dim3(1024), 256, 0, stream>>>(phiA, phiB, vt, out);
}